// Round 3
// baseline (741.654 us; speedup 1.0000x reference)
//
#include <hip/hip_runtime.h>

// Problem constants (fixed by setup_inputs)
#define D      1024
#define H      16
#define HD     64
#define SQ     16          // Q_LEN
#define SP     32752       // START_POS
#define TT     32768       // total attended keys
#define SCALE  0.125f
#define NC     128         // chunks
#define CHUNK  256         // keys per chunk (NC*CHUNK == TT)
#define PSTR   260         // p_s row stride in floats: 16B-aligned, 260%32==4 -> 2-way banks (free)

__device__ __forceinline__ float4 ldg4(const float* p){ return *reinterpret_cast<const float4*>(p); }
__device__ __forceinline__ void   stg4(float* p, float4 v){ *reinterpret_cast<float4*>(p) = v; }

// y[16 x 1024] = x[16 x 1024] @ W^T, one 16-row chunk of W per block (256 thr).
__device__ __forceinline__ float gemm16_val(const float* __restrict__ x,
                                            const float* __restrict__ W,
                                            int ochunk, int* o_out, int* li_out)
{
    const int t  = threadIdx.x;
    const int o  = ochunk * 16 + (t >> 4);
    const int ds = (t & 15) << 6;   // *64

    float4 wv[16];
    const float* wp = W + (size_t)o * D + ds;
    #pragma unroll
    for (int d4 = 0; d4 < 16; ++d4) wv[d4] = ldg4(wp + d4 * 4);

    float a[16];
    #pragma unroll
    for (int i = 0; i < 16; ++i) {
        const float* xp = x + (size_t)i * D + ds;
        float s = 0.f;
        #pragma unroll
        for (int d4 = 0; d4 < 16; ++d4) {
            float4 xv = ldg4(xp + d4 * 4);
            s += wv[d4].x * xv.x + wv[d4].y * xv.y + wv[d4].z * xv.z + wv[d4].w * xv.w;
        }
        a[i] = s;
    }
    #pragma unroll
    for (int off = 8; off >= 1; off >>= 1) {
        #pragma unroll
        for (int i = 0; i < 16; ++i) a[i] += __shfl_xor(a[i], off, 16);
    }
    const int li = t & 15;
    float v = a[0];
    #pragma unroll
    for (int i = 1; i < 16; ++i) v = (li == i) ? a[i] : v;
    *o_out = o; *li_out = li;
    return v;
}

__global__ __launch_bounds__(256) void qkv_proj(
    const float* __restrict__ q,
    const float* __restrict__ Wq, const float* __restrict__ Wk, const float* __restrict__ Wv,
    float* __restrict__ Qws, float* __restrict__ out,
    float* __restrict__ ck, float* __restrict__ cv)
{
    const int m      = blockIdx.x >> 6;   // 0=Q,1=K,2=V
    const int ochunk = blockIdx.x & 63;
    const float* W = (m == 0) ? Wq : (m == 1) ? Wk : Wv;
    int o, li;
    float v = gemm16_val(q, W, ochunk, &o, &li);
    if (m == 0) {
        Qws[li * D + o] = v;
    } else if (m == 1) {
        out[16384 + li * D + o] = v;                 // output 1: K
        ck[(size_t)(SP + li) * D + o] = v;           // KV-cache update
    } else {
        out[32768 + li * D + o] = v;                 // output 2: V
        cv[(size_t)(SP + li) * D + o] = v;
    }
}

__global__ __launch_bounds__(256) void out_proj(
    const float* __restrict__ O, const float* __restrict__ Wo, float* __restrict__ out)
{
    int o, li;
    float v = gemm16_val(O, Wo, blockIdx.x, &o, &li);
    out[li * D + o] = v;                             // output 0
}

// Flash-decode partials, fully coalesced.
// grid: 16 heads x 128 chunks of 256 keys; block 256 thr (4 waves).
// Scores: wave reads 4 rows x 16 contiguous float4 / instr; butterfly-16 reduce.
// PV: V staged in 64-row LDS subtiles (XOR swizzle, conflict-free).
__global__ __launch_bounds__(256, 4) void attn_partial(
    const float* __restrict__ Qws, const float* __restrict__ K, const float* __restrict__ V,
    float* __restrict__ num, float* __restrict__ den)
{
    __shared__ __align__(16) float p_s[16 * PSTR];   // exp'd scores [i][r], 16.6 KB
    __shared__ __align__(16) float v_s[64 * 64];     // V subtile, XOR-swizzled, 16 KB

    const int t     = threadIdx.x;
    const int h     = blockIdx.x & 15;
    const int c     = blockIdx.x >> 4;               // 0..127
    const int cbase = c * CHUNK;
    const int w     = t >> 6;                        // wave id 0..3
    const int l     = t & 63;
    const int rr    = l >> 4;                        // row-in-group 0..3
    const int d4    = l & 15;                        // dim quad 0..15

    // ---- preload Q fragments: q4[i] = Q[i][h*64 + d4*4 ..] (broadcast-friendly) ----
    float4 q4[16];
    #pragma unroll
    for (int i = 0; i < 16; ++i)
        q4[i] = ldg4(Qws + (size_t)i * D + h * HD + d4 * 4);

    // ---- scores: wave w owns rows [w*64, w*64+64), 4 rows per iter (coalesced) ----
    for (int it = 0; it < 16; ++it) {
        const int r = w * 64 + it * 4 + rr;          // chunk-local row
        const float4 k4 = ldg4(K + (size_t)(cbase + r) * D + h * HD + d4 * 4);
        float s[16];
        #pragma unroll
        for (int i = 0; i < 16; ++i)
            s[i] = k4.x * q4[i].x + k4.y * q4[i].y + k4.z * q4[i].z + k4.w * q4[i].w;
        // butterfly over the 16 d4-lanes: lane d4 ends with s[0] = score[i=d4][row r]
        #pragma unroll
        for (int off = 8; off >= 1; off >>= 1) {
            #pragma unroll
            for (int i = 0; i < off; ++i) {
                float mine = (d4 & off) ? s[i + off] : s[i];
                float send = (d4 & off) ? s[i]       : s[i + off];
                s[i] = mine + __shfl_xor(send, off, 16);
            }
        }
        const int j = cbase + r;                     // global key index
        float p = (j > SP + d4) ? 0.f : __expf(s[0] * SCALE);
        p_s[d4 * PSTR + r] = p;                      // banks (4*d4+r)%32: 2-way, free
    }
    __syncthreads();

    // ---- PV: thread (i, dq) accumulates o[i][dq-quad] over all 256 rows ----
    const int i  = t >> 4;                           // query row 0..15
    const int dq = t & 15;                           // dim quad 0..15
    float4 o = make_float4(0.f, 0.f, 0.f, 0.f);
    float dsum = 0.f;

    for (int sb = 0; sb < 4; ++sb) {
        // stage V rows [sb*64, sb*64+64) into LDS, coalesced, XOR-swizzled
        #pragma unroll
        for (int step = 0; step < 4; ++step) {
            const int lr = step * 16 + i;            // 0..63
            const int gj = cbase + sb * 64 + lr;
            float4 v = ldg4(V + (size_t)gj * D + h * HD + dq * 4);
            stg4(&v_s[lr * 64 + ((dq ^ (lr & 15)) << 2)], v);
        }
        __syncthreads();

        #pragma unroll
        for (int rb = 0; rb < 16; ++rb) {
            float4 p4 = *reinterpret_cast<const float4*>(&p_s[i * PSTR + sb * 64 + rb * 4]);
            const int r0 = rb * 4;
            float4 v0 = *reinterpret_cast<const float4*>(&v_s[(r0 + 0) * 64 + ((dq ^ ((r0 + 0) & 15)) << 2)]);
            float4 v1 = *reinterpret_cast<const float4*>(&v_s[(r0 + 1) * 64 + ((dq ^ ((r0 + 1) & 15)) << 2)]);
            float4 v2 = *reinterpret_cast<const float4*>(&v_s[(r0 + 2) * 64 + ((dq ^ ((r0 + 2) & 15)) << 2)]);
            float4 v3 = *reinterpret_cast<const float4*>(&v_s[(r0 + 3) * 64 + ((dq ^ ((r0 + 3) & 15)) << 2)]);
            o.x += p4.x * v0.x + p4.y * v1.x + p4.z * v2.x + p4.w * v3.x;
            o.y += p4.x * v0.y + p4.y * v1.y + p4.z * v2.y + p4.w * v3.y;
            o.z += p4.x * v0.z + p4.y * v1.z + p4.z * v2.z + p4.w * v3.z;
            o.w += p4.x * v0.w + p4.y * v1.w + p4.z * v2.w + p4.w * v3.w;
            dsum += p4.x + p4.y + p4.z + p4.w;
        }
        __syncthreads();
    }

    float* np = num + ((size_t)((h * NC + c) * 16 + i)) * 64 + dq * 4;
    stg4(np, o);
    if (dq == 0) den[(h * NC + c) * 16 + i] = dsum;
}

// O[i][h*64+d] = sum_c num / sum_c den
__global__ __launch_bounds__(256) void combine(
    const float* __restrict__ num, const float* __restrict__ den, float* __restrict__ O)
{
    const int idx = blockIdx.x * 256 + threadIdx.x;  // [i][h][d]
    const int d  = idx & 63;
    const int hh = (idx >> 6) & 15;
    const int i  = idx >> 10;
    float ns = 0.f, ds = 0.f;
    #pragma unroll 8
    for (int c = 0; c < NC; ++c) {
        ns += num[((size_t)(hh * NC + c) * 16 + i) * 64 + d];
        ds += den[(hh * NC + c) * 16 + i];
    }
    O[idx] = ns / ds;
}

extern "C" void kernel_launch(void* const* d_in, const int* in_sizes, int n_in,
                              void* d_out, int out_size, void* d_ws, size_t ws_size,
                              hipStream_t stream)
{
    (void)in_sizes; (void)n_in; (void)out_size; (void)ws_size;
    const float* q  = (const float*)d_in[0];
    const float* Wq = (const float*)d_in[1];
    const float* Wk = (const float*)d_in[2];
    const float* Wv = (const float*)d_in[3];
    const float* Wo = (const float*)d_in[4];
    float* ck  = (float*)d_in[5];   // cache_k (restored from pristine each launch)
    float* cv  = (float*)d_in[6];   // cache_v
    float* out = (float*)d_out;

    float* ws  = (float*)d_ws;
    float* Qws = ws;                                   // 16384
    float* num = ws + 16384;                           // 16*NC*16*64 = 2097152
    float* den = num + (size_t)16 * NC * 16 * 64;      // 32768
    float* O   = den + 16 * NC * 16;                   // 16384

    qkv_proj    <<<192,     256, 0, stream>>>(q, Wq, Wk, Wv, Qws, out, ck, cv);
    attn_partial<<<16 * NC, 256, 0, stream>>>(Qws, ck, cv, num, den);
    combine     <<<64,      256, 0, stream>>>(num, den, O);
    out_proj    <<<64,      256, 0, stream>>>(O, Wo, out);
}

// Round 4
// 569.500 us; speedup vs baseline: 1.3023x; 1.3023x over previous
//
#include <hip/hip_runtime.h>

// Problem constants (fixed by setup_inputs)
#define D      1024
#define H      16
#define HD     64
#define SQ     16          // Q_LEN
#define SP     32752       // START_POS
#define TT     32768       // total attended keys
#define SCALE  0.125f
#define NC     128         // chunks
#define CHUNK  256         // keys per chunk (NC*CHUNK == TT)
#define PSTR   260         // p_s row stride in floats: 16B-aligned, 260%32==4 -> 2-way banks (free)

__device__ __forceinline__ float4 ldg4(const float* p){ return *reinterpret_cast<const float4*>(p); }
__device__ __forceinline__ void   stg4(float* p, float4 v){ *reinterpret_cast<float4*>(p) = v; }

// y[16 x 1024] = x[16 x 1024] @ W^T, one 16-row chunk of W per block (256 thr).
__device__ __forceinline__ float gemm16_val(const float* __restrict__ x,
                                            const float* __restrict__ W,
                                            int ochunk, int* o_out, int* li_out)
{
    const int t  = threadIdx.x;
    const int o  = ochunk * 16 + (t >> 4);
    const int ds = (t & 15) << 6;   // *64

    float4 wv[16];
    const float* wp = W + (size_t)o * D + ds;
    #pragma unroll
    for (int d4 = 0; d4 < 16; ++d4) wv[d4] = ldg4(wp + d4 * 4);

    float a[16];
    #pragma unroll
    for (int i = 0; i < 16; ++i) {
        const float* xp = x + (size_t)i * D + ds;
        float s = 0.f;
        #pragma unroll
        for (int d4 = 0; d4 < 16; ++d4) {
            float4 xv = ldg4(xp + d4 * 4);
            s += wv[d4].x * xv.x + wv[d4].y * xv.y + wv[d4].z * xv.z + wv[d4].w * xv.w;
        }
        a[i] = s;
    }
    #pragma unroll
    for (int off = 8; off >= 1; off >>= 1) {
        #pragma unroll
        for (int i = 0; i < 16; ++i) a[i] += __shfl_xor(a[i], off, 16);
    }
    const int li = t & 15;
    float v = a[0];
    #pragma unroll
    for (int i = 1; i < 16; ++i) v = (li == i) ? a[i] : v;
    *o_out = o; *li_out = li;
    return v;
}

__global__ __launch_bounds__(256) void qkv_proj(
    const float* __restrict__ q,
    const float* __restrict__ Wq, const float* __restrict__ Wk, const float* __restrict__ Wv,
    float* __restrict__ Qws, float* __restrict__ out,
    float* __restrict__ ck, float* __restrict__ cv)
{
    const int m      = blockIdx.x >> 6;   // 0=Q,1=K,2=V
    const int ochunk = blockIdx.x & 63;
    const float* W = (m == 0) ? Wq : (m == 1) ? Wk : Wv;
    int o, li;
    float v = gemm16_val(q, W, ochunk, &o, &li);
    if (m == 0) {
        Qws[li * D + o] = v;
    } else if (m == 1) {
        out[16384 + li * D + o] = v;                 // output 1: K
        ck[(size_t)(SP + li) * D + o] = v;           // KV-cache update
    } else {
        out[32768 + li * D + o] = v;                 // output 2: V
        cv[(size_t)(SP + li) * D + o] = v;
    }
}

__global__ __launch_bounds__(256) void out_proj(
    const float* __restrict__ O, const float* __restrict__ Wo, float* __restrict__ out)
{
    int o, li;
    float v = gemm16_val(O, Wo, blockIdx.x, &o, &li);
    out[li * D + o] = v;                             // output 0
}

// Flash-decode partials, coalesced + low register pressure.
// grid: 16 heads x 128 chunks of 256 keys; block 256 thr (4 waves).
// Scores: lanes (rr,d4) read 4 rows x 16 quads = 1KB/instr; Q frags read from LDS
//         (16 addrs, 4-way broadcast, 2-way banks = free); butterfly-16 reduce.
// PV: V staged in 64-row LDS subtiles (verbatim from R3, correctness-proven).
__global__ __launch_bounds__(256) void attn_partial(
    const float* __restrict__ Qws, const float* __restrict__ K, const float* __restrict__ V,
    float* __restrict__ num, float* __restrict__ den)
{
    __shared__ __align__(16) float4 q_s4[256];       // [i][d4], 4 KB
    __shared__ __align__(16) float p_s[16 * PSTR];   // exp'd scores [i][r], 16.6 KB
    __shared__ __align__(16) float v_s[64 * 64];     // V subtile, XOR-swizzled, 16 KB

    const int t     = threadIdx.x;
    const int h     = blockIdx.x & 15;
    const int c     = blockIdx.x >> 4;               // 0..127
    const int cbase = c * CHUNK;
    const int w     = t >> 6;                        // wave id 0..3
    const int l     = t & 63;
    const int rr    = l >> 4;                        // row-in-group 0..3
    const int d4    = l & 15;                        // dim quad 0..15

    // stage Q[head] (16x64) into LDS
    {
        const int i = t >> 4, dq = t & 15;
        q_s4[t] = ldg4(Qws + (size_t)i * D + h * HD + dq * 4);
    }
    __syncthreads();

    // ---- scores: wave w owns rows [w*64, w*64+64), 4 rows per iter (coalesced) ----
    for (int it = 0; it < 16; ++it) {
        const int r = w * 64 + it * 4 + rr;          // chunk-local row
        const float4 k4 = ldg4(K + (size_t)(cbase + r) * D + h * HD + d4 * 4);
        float s[16];
        #pragma unroll
        for (int i = 0; i < 16; ++i) {
            float4 q4 = q_s4[i * 16 + d4];
            s[i] = k4.x * q4.x + k4.y * q4.y + k4.z * q4.z + k4.w * q4.w;
        }
        // butterfly over the 16 d4-lanes: lane d4 ends with s[0] = score[i=d4][row r]
        #pragma unroll
        for (int off = 8; off >= 1; off >>= 1) {
            #pragma unroll
            for (int i = 0; i < off; ++i) {
                float mine = (d4 & off) ? s[i + off] : s[i];
                float send = (d4 & off) ? s[i]       : s[i + off];
                s[i] = mine + __shfl_xor(send, off, 16);
            }
        }
        const int j = cbase + r;                     // global key index
        float p = (j > SP + d4) ? 0.f : __expf(s[0] * SCALE);
        p_s[d4 * PSTR + r] = p;                      // banks (4*d4+rr): 2-way, free
    }
    __syncthreads();

    // ---- PV: thread (i, dq) accumulates o[i][dq-quad] over all 256 rows ----
    const int i  = t >> 4;                           // query row 0..15
    const int dq = t & 15;                           // dim quad 0..15
    float4 o = make_float4(0.f, 0.f, 0.f, 0.f);
    float dsum = 0.f;

    for (int sb = 0; sb < 4; ++sb) {
        // stage V rows [sb*64, sb*64+64) into LDS, coalesced, XOR-swizzled
        #pragma unroll
        for (int step = 0; step < 4; ++step) {
            const int lr = step * 16 + i;            // 0..63
            const int gj = cbase + sb * 64 + lr;
            float4 v = ldg4(V + (size_t)gj * D + h * HD + dq * 4);
            stg4(&v_s[lr * 64 + ((dq ^ (lr & 15)) << 2)], v);
        }
        __syncthreads();

        #pragma unroll
        for (int rb = 0; rb < 16; ++rb) {
            float4 p4 = *reinterpret_cast<const float4*>(&p_s[i * PSTR + sb * 64 + rb * 4]);
            const int r0 = rb * 4;
            float4 v0 = *reinterpret_cast<const float4*>(&v_s[(r0 + 0) * 64 + ((dq ^ ((r0 + 0) & 15)) << 2)]);
            float4 v1 = *reinterpret_cast<const float4*>(&v_s[(r0 + 1) * 64 + ((dq ^ ((r0 + 1) & 15)) << 2)]);
            float4 v2 = *reinterpret_cast<const float4*>(&v_s[(r0 + 2) * 64 + ((dq ^ ((r0 + 2) & 15)) << 2)]);
            float4 v3 = *reinterpret_cast<const float4*>(&v_s[(r0 + 3) * 64 + ((dq ^ ((r0 + 3) & 15)) << 2)]);
            o.x += p4.x * v0.x + p4.y * v1.x + p4.z * v2.x + p4.w * v3.x;
            o.y += p4.x * v0.y + p4.y * v1.y + p4.z * v2.y + p4.w * v3.y;
            o.z += p4.x * v0.z + p4.y * v1.z + p4.z * v2.z + p4.w * v3.z;
            o.w += p4.x * v0.w + p4.y * v1.w + p4.z * v2.w + p4.w * v3.w;
            dsum += p4.x + p4.y + p4.z + p4.w;
        }
        __syncthreads();
    }

    float* np = num + ((size_t)((h * NC + c) * 16 + i)) * 64 + dq * 4;
    stg4(np, o);
    if (dq == 0) den[(h * NC + c) * 16 + i] = dsum;
}

// O[i][h*64+d] = sum_c num / sum_c den
__global__ __launch_bounds__(256) void combine(
    const float* __restrict__ num, const float* __restrict__ den, float* __restrict__ O)
{
    const int idx = blockIdx.x * 256 + threadIdx.x;  // [i][h][d]
    const int d  = idx & 63;
    const int hh = (idx >> 6) & 15;
    const int i  = idx >> 10;
    float ns = 0.f, ds = 0.f;
    #pragma unroll 8
    for (int c = 0; c < NC; ++c) {
        ns += num[((size_t)(hh * NC + c) * 16 + i) * 64 + d];
        ds += den[(hh * NC + c) * 16 + i];
    }
    O[idx] = ns / ds;
}

extern "C" void kernel_launch(void* const* d_in, const int* in_sizes, int n_in,
                              void* d_out, int out_size, void* d_ws, size_t ws_size,
                              hipStream_t stream)
{
    (void)in_sizes; (void)n_in; (void)out_size; (void)ws_size;
    const float* q  = (const float*)d_in[0];
    const float* Wq = (const float*)d_in[1];
    const float* Wk = (const float*)d_in[2];
    const float* Wv = (const float*)d_in[3];
    const float* Wo = (const float*)d_in[4];
    float* ck  = (float*)d_in[5];   // cache_k (restored from pristine each launch)
    float* cv  = (float*)d_in[6];   // cache_v
    float* out = (float*)d_out;

    float* ws  = (float*)d_ws;
    float* Qws = ws;                                   // 16384
    float* num = ws + 16384;                           // 16*NC*16*64 = 2097152
    float* den = num + (size_t)16 * NC * 16 * 64;      // 32768
    float* O   = den + 16 * NC * 16;                   // 16384

    qkv_proj    <<<192,     256, 0, stream>>>(q, Wq, Wk, Wv, Qws, out, ck, cv);
    attn_partial<<<16 * NC, 256, 0, stream>>>(Qws, ck, cv, num, den);
    combine     <<<64,      256, 0, stream>>>(num, den, O);
    out_proj    <<<64,      256, 0, stream>>>(O, Wo, out);
}